// Round 4
// baseline (48.989 us; speedup 1.0000x reference)
//
#include <hip/hip_runtime.h>
#include <math.h>

typedef _Float16 half8 __attribute__((ext_vector_type(8)));
typedef float f32x16 __attribute__((ext_vector_type(16)));

#define DIMK 2048
#define NEXP 64
#define BM 64               // rows per block
#define NW 8                // waves per block (k-split)
#define KPW (DIMK / NW)     // 256 k per wave
#define KSTEP 16            // k per 32x32x16 MFMA step
#define NKS (KPW / KSTEP)   // 16 ksteps per wave
#define RA 4                // A ring depth (HBM latency cover)
#define RW 2                // W ring depth (L2 latency cover)

__device__ __forceinline__ bool gt_pair(float v, int i, float v2, int i2) {
    return (v > v2) || (v == v2 && i < i2);
}

__global__ __launch_bounds__(512, 2)
void SwitchRouter_43078521979510_kernel(const float* __restrict__ x,
                                        const float* __restrict__ W,
                                        const float* __restrict__ bias,
                                        float* __restrict__ out, int M)
{
    __shared__ float red[4 * 64 * 68];   // 69632 B reduction scratch

    const int t    = threadIdx.x;
    const int wv   = t >> 6;
    const int lane = t & 63;
    const int col  = lane & 31;   // A row within tile / W expert within et-group
    const int kg   = lane >> 5;   // k sub-slice selector (frag: k = 8*kg + j)
    const int r0   = blockIdx.x * BM;

    const float* xb = x + (size_t)(r0 + col) * DIMK + wv * KPW + kg * 8;
    const float* wb = W + (size_t)col * DIMK + wv * KPW + kg * 8;

    f32x16 acc[2][2] = {};           // [row-tile][expert-tile]
    float4 rgA[RA][2][2];            // [depth][row-tile][half]
    float4 rgW[RW][2][2];            // [depth][expert-tile][half]

    // ---- prologue: fill rings ----
#pragma unroll
    for (int d = 0; d < RA; ++d)
#pragma unroll
        for (int tl = 0; tl < 2; ++tl)
#pragma unroll
            for (int h = 0; h < 2; ++h)
                rgA[d][tl][h] = *(const float4*)(xb + (size_t)tl * 32 * DIMK + d * KSTEP + h * 4);
#pragma unroll
    for (int d = 0; d < RW; ++d)
#pragma unroll
        for (int et = 0; et < 2; ++et)
#pragma unroll
            for (int h = 0; h < 2; ++h)
                rgW[d][et][h] = *(const float4*)(wb + (size_t)et * 32 * DIMK + d * KSTEP + h * 4);

    // ---- main loop: fully unrolled, static ring indices ----
#pragma unroll
    for (int ks = 0; ks < NKS; ++ks) {
        const int ia = ks % RA;
        const int iw = ks % RW;

        half8 a0[2], a1[2], w0[2], w1[2];
#pragma unroll
        for (int tl = 0; tl < 2; ++tl) {
            const float4 va = rgA[ia][tl][0], vb2 = rgA[ia][tl][1];
            const float f[8] = {va.x, va.y, va.z, va.w, vb2.x, vb2.y, vb2.z, vb2.w};
#pragma unroll
            for (int j = 0; j < 8; ++j) {
                _Float16 h = (_Float16)f[j];
                a0[tl][j] = h;
                a1[tl][j] = (_Float16)(f[j] - (float)h);
            }
        }
#pragma unroll
        for (int et = 0; et < 2; ++et) {
            const float4 va = rgW[iw][et][0], vb2 = rgW[iw][et][1];
            const float f[8] = {va.x, va.y, va.z, va.w, vb2.x, vb2.y, vb2.z, vb2.w};
#pragma unroll
            for (int j = 0; j < 8; ++j) {
                _Float16 h = (_Float16)f[j];
                w0[et][j] = h;
                w1[et][j] = (_Float16)(f[j] - (float)h);
            }
        }

        // refill rings (issued before MFMA so latency hides under compute)
        if (ks + RA < NKS) {
#pragma unroll
            for (int tl = 0; tl < 2; ++tl)
#pragma unroll
                for (int h = 0; h < 2; ++h)
                    rgA[ia][tl][h] = *(const float4*)(xb + (size_t)tl * 32 * DIMK + (ks + RA) * KSTEP + h * 4);
        }
        if (ks + RW < NKS) {
#pragma unroll
            for (int et = 0; et < 2; ++et)
#pragma unroll
                for (int h = 0; h < 2; ++h)
                    rgW[iw][et][h] = *(const float4*)(wb + (size_t)et * 32 * DIMK + (ks + RW) * KSTEP + h * 4);
        }

#pragma unroll
        for (int tl = 0; tl < 2; ++tl)
#pragma unroll
            for (int et = 0; et < 2; ++et) {
                acc[tl][et] = __builtin_amdgcn_mfma_f32_32x32x16_f16(a0[tl], w0[et], acc[tl][et], 0, 0, 0);
                acc[tl][et] = __builtin_amdgcn_mfma_f32_32x32x16_f16(a1[tl], w0[et], acc[tl][et], 0, 0, 0);
                acc[tl][et] = __builtin_amdgcn_mfma_f32_32x32x16_f16(a0[tl], w1[et], acc[tl][et], 0, 0, 0);
            }
    }

    // ---- 3-stage pairwise cross-wave reduction (8 -> 4 -> 2 -> 1 partials) ----
    // D frag (32x32): col = lane&31, row m = (rg&3) + 8*(rg>>2) + 4*kg
#define TILE_STORE(slot)                                                        \
    {                                                                           \
        _Pragma("unroll") for (int tl = 0; tl < 2; ++tl)                        \
        _Pragma("unroll") for (int et = 0; et < 2; ++et)                        \
        _Pragma("unroll") for (int rg = 0; rg < 16; ++rg) {                     \
            const int m = (rg & 3) + 8 * (rg >> 2) + 4 * kg;                    \
            red[((slot) * 64 + tl * 32 + m) * 68 + et * 32 + col] = acc[tl][et][rg]; \
        }                                                                       \
    }
#define TILE_ADD(slot)                                                          \
    {                                                                           \
        _Pragma("unroll") for (int tl = 0; tl < 2; ++tl)                        \
        _Pragma("unroll") for (int et = 0; et < 2; ++et)                        \
        _Pragma("unroll") for (int rg = 0; rg < 16; ++rg) {                     \
            const int m = (rg & 3) + 8 * (rg >> 2) + 4 * kg;                    \
            acc[tl][et][rg] += red[((slot) * 64 + tl * 32 + m) * 68 + et * 32 + col]; \
        }                                                                       \
    }

    if (wv & 1) TILE_STORE(wv >> 1);           // waves 1,3,5,7 -> slots 0..3
    __syncthreads();
    if (!(wv & 1)) TILE_ADD(wv >> 1);          // waves 0,2,4,6 absorb partners
    __syncthreads();
    if (wv == 2 || wv == 6) TILE_STORE(wv >> 2);  // -> slots 0,1
    __syncthreads();
    if (wv == 0 || wv == 4) TILE_ADD(wv >> 2);
    __syncthreads();
    if (wv == 4) TILE_STORE(0);
    __syncthreads();
    if (wv == 0) {
        TILE_ADD(0);
        // write final logit sums (no bias yet) to slot 0
#pragma unroll
        for (int tl = 0; tl < 2; ++tl)
#pragma unroll
            for (int et = 0; et < 2; ++et)
#pragma unroll
                for (int rg = 0; rg < 16; ++rg) {
                    const int m = (rg & 3) + 8 * (rg >> 2) + 4 * kg;
                    red[(tl * 32 + m) * 68 + et * 32 + col] = acc[tl][et][rg];
                }
    }
    __syncthreads();

    // ---- epilogue: bias + stable top-2 + softmax (validated path), all 512 threads ----
    {
        const int row = t >> 3;   // 0..63
        const int g8  = t & 7;    // expert group of 8
        float l[8];
#pragma unroll
        for (int j = 0; j < 8; ++j)
            l[j] = red[row * 68 + g8 * 8 + j] + bias[g8 * 8 + j];

        float v0 = l[0];
        int   i0 = 8 * g8;
        float v1 = -INFINITY;
        int   i1 = -1;
#pragma unroll
        for (int j = 1; j < 8; ++j) {
            const float lv = l[j];
            const int   e  = 8 * g8 + j;
            if (lv > v0) { v1 = v0; i1 = i0; v0 = lv; i0 = e; }
            else if (lv > v1) { v1 = lv; i1 = e; }
        }
#pragma unroll
        for (int m2 = 1; m2 <= 4; m2 <<= 1) {
            const float ov0 = __shfl_xor(v0, m2);
            const int   oi0 = __shfl_xor(i0, m2);
            const float ov1 = __shfl_xor(v1, m2);
            const int   oi1 = __shfl_xor(i1, m2);
            if (gt_pair(ov0, oi0, v0, i0)) {
                if (gt_pair(v0, i0, ov1, oi1)) { v1 = v0; i1 = i0; }
                else                           { v1 = ov1; i1 = oi1; }
                v0 = ov0; i0 = oi0;
            } else if (gt_pair(ov0, oi0, v1, i1)) {
                v1 = ov0; i1 = oi0;
            }
        }
        float d = 0.f;
#pragma unroll
        for (int j = 0; j < 8; ++j) d += expf(l[j] - v0);
#pragma unroll
        for (int m2 = 1; m2 <= 4; m2 <<= 1) d += __shfl_xor(d, m2);

        if (g8 == 0) {
            const int R = r0 + row;
            out[2 * R]     = (float)i0;
            out[2 * R + 1] = (float)i1;
            out[2 * M + 2 * R]     = 1.f / d;
            out[2 * M + 2 * R + 1] = expf(v1 - v0) / d;
        }
    }
}

extern "C" void kernel_launch(void* const* d_in, const int* in_sizes, int n_in,
                              void* d_out, int out_size, void* d_ws, size_t ws_size,
                              hipStream_t stream) {
    const float* x  = (const float*)d_in[0];
    const float* W  = (const float*)d_in[1];
    const float* b  = (const float*)d_in[2];
    float* out = (float*)d_out;
    const int M = in_sizes[0] / DIMK;   // 16384 rows
    SwitchRouter_43078521979510_kernel<<<M / BM, 512, 0, stream>>>(x, W, b, out, M);
}

// Round 5
// 45.907 us; speedup vs baseline: 1.0672x; 1.0672x over previous
//
#include <hip/hip_runtime.h>
#include <math.h>

typedef _Float16 half8 __attribute__((ext_vector_type(8)));
typedef float f32x4 __attribute__((ext_vector_type(4)));

#define DIMK 2048
#define NEXP 64
#define BM 32                 // rows per block
#define NW 8                  // waves per block (k-split)
#define KPW (DIMK / NW)       // 256 k per wave
#define CHUNK 32              // k per staged chunk (one 16x16x32 kstep)
#define NCHUNK (KPW / CHUNK)  // 8 chunks per wave

__device__ __forceinline__ bool gt_pair(float v, int i, float v2, int i2) {
    return (v > v2) || (v == v2 && i < i2);
}

__global__ __launch_bounds__(512, 4)
void SwitchRouter_43078521979510_kernel(const float* __restrict__ x,
                                        const float* __restrict__ W,
                                        const float* __restrict__ bias,
                                        float* __restrict__ out, int M)
{
    __shared__ float lds[16384];   // 64 KB: 8 waves x dbuf x (32 rows x 32 k fp32); aliased by reduction

    const int t     = threadIdx.x;
    const int wv    = t >> 6;
    const int lane  = t & 63;
    const int col16 = lane & 15;   // A row within 16-tile / W expert within et-group
    const int kg    = lane >> 2 >> 2; // lane>>4: k-slice selector 0..3
    const int r0    = blockIdx.x * BM;
    const int kwb   = wv * KPW;

    // staging decomposition: instr j covers rows j*8 + (lane>>3), granule (lane&7) [XOR-swizzled]
    const int srow = lane >> 3;
    const int sg   = lane & 7;

    const float* xbase = x + (size_t)r0 * DIMK + kwb;
    float* abase = lds + wv * 2048;     // 2 bufs x 1024 floats

    // W: lane reads expert et*16+col16, k-slice kg*8 (+h*4), fp32 from L2
    const float* wbase = W + (size_t)col16 * DIMK + kwb + kg * 8;

#define STAGE(c)                                                                   \
    {                                                                              \
        float* dst = abase + ((c) & 1) * 1024;                                     \
        const int kc = (c) * CHUNK;                                                \
        _Pragma("unroll") for (int j = 0; j < 4; ++j) {                            \
            const int row = j * 8 + srow;                                          \
            const float* src = xbase + (size_t)row * DIMK + kc                     \
                               + ((sg ^ (row & 7)) << 2);                          \
            __builtin_amdgcn_global_load_lds(                                      \
                (const __attribute__((address_space(1))) void*)src,                \
                (__attribute__((address_space(3))) void*)(dst + j * 256),          \
                16, 0, 0);                                                         \
        }                                                                          \
    }

#define LOADW(c)                                                                   \
    {                                                                              \
        _Pragma("unroll") for (int et = 0; et < 4; ++et)                           \
        _Pragma("unroll") for (int h = 0; h < 2; ++h)                              \
            wbuf[et][h] = *(const float4*)(wbase + (size_t)et * 16 * DIMK          \
                                           + (c) * CHUNK + h * 4);                 \
    }

    float4 wbuf[4][2];
    f32x4 acc[2][4] = {};   // [row-tile 16][expert-tile 16]

    // prologue (program order fixes the vmcnt ledger): A(0)[4], W(0)[8], A(1)[4]
    STAGE(0);
    LOADW(0);
    STAGE(1);

    for (int c = 0; c < NCHUNK; ++c) {
        // retire A(c)+W(c); leave A(c+1) (4 youngest) in flight
        if (c == NCHUNK - 1) {
            asm volatile("s_waitcnt vmcnt(0)" ::: "memory");
        } else {
            asm volatile("s_waitcnt vmcnt(4)" ::: "memory");
        }

        // ---- convert W fp32 -> f16 limbs (frees wbuf for next issue) ----
        half8 w0[4], w1[4];
#pragma unroll
        for (int et = 0; et < 4; ++et) {
            const float4 va = wbuf[et][0], vb = wbuf[et][1];
            const float f[8] = {va.x, va.y, va.z, va.w, vb.x, vb.y, vb.z, vb.w};
#pragma unroll
            for (int j = 0; j < 8; ++j) {
                _Float16 h = (_Float16)f[j];
                w0[et][j] = h;
                w1[et][j] = (_Float16)(f[j] - (float)h);
            }
        }

        // ---- A fragment reads (XOR-swizzled granules) ----
        const float* buf = abase + (c & 1) * 1024;
        float4 fa[2], fb[2];
#pragma unroll
        for (int tl = 0; tl < 2; ++tl) {
            const int r  = tl * 16 + col16;
            const int s0 = (2 * kg) ^ (r & 7);
            fa[tl] = *(const float4*)(buf + r * 32 + (s0 << 2));
            fb[tl] = *(const float4*)(buf + r * 32 + ((s0 ^ 1) << 2));
        }

        // ---- issue next-chunk loads (exactly 8 W + 4 A VMEM ops per region) ----
        if (c + 1 < NCHUNK) LOADW(c + 1);
        if (c + 2 < NCHUNK) STAGE(c + 2);

        // ---- convert A + MFMA ----
#pragma unroll
        for (int tl = 0; tl < 2; ++tl) {
            const float4 va = fa[tl], vb = fb[tl];
            const float f[8] = {va.x, va.y, va.z, va.w, vb.x, vb.y, vb.z, vb.w};
            half8 a0, a1;
#pragma unroll
            for (int j = 0; j < 8; ++j) {
                _Float16 h = (_Float16)f[j];
                a0[j] = h;
                a1[j] = (_Float16)(f[j] - (float)h);
            }
#pragma unroll
            for (int et = 0; et < 4; ++et) {
                acc[tl][et] = __builtin_amdgcn_mfma_f32_16x16x32_f16(a0, w0[et], acc[tl][et], 0, 0, 0);
                acc[tl][et] = __builtin_amdgcn_mfma_f32_16x16x32_f16(a1, w0[et], acc[tl][et], 0, 0, 0);
                acc[tl][et] = __builtin_amdgcn_mfma_f32_16x16x32_f16(a0, w1[et], acc[tl][et], 0, 0, 0);
            }
        }
    }

    // ---------------- cross-wave K reduction (pairwise tree, 8 -> 1) ----------------
    // D frag (16x16): col = lane&15, row m = (lane>>4)*4 + r
    __syncthreads();
    float* red = lds;   // 4 slots x 32 rows x 68 = 8704 floats (aliases A space)

#define TILE_STORE(slot)                                                           \
    {                                                                              \
        _Pragma("unroll") for (int tl = 0; tl < 2; ++tl)                           \
        _Pragma("unroll") for (int et = 0; et < 4; ++et)                           \
        _Pragma("unroll") for (int r = 0; r < 4; ++r) {                            \
            const int m = (kg << 2) + r;                                           \
            red[(slot) * 2176 + (tl * 16 + m) * 68 + et * 16 + col16] = acc[tl][et][r]; \
        }                                                                          \
    }
#define TILE_ADD(slot)                                                             \
    {                                                                              \
        _Pragma("unroll") for (int tl = 0; tl < 2; ++tl)                           \
        _Pragma("unroll") for (int et = 0; et < 4; ++et)                           \
        _Pragma("unroll") for (int r = 0; r < 4; ++r) {                            \
            const int m = (kg << 2) + r;                                           \
            acc[tl][et][r] += red[(slot) * 2176 + (tl * 16 + m) * 68 + et * 16 + col16]; \
        }                                                                          \
    }

    if (wv & 1) TILE_STORE(wv >> 1);            // waves 1,3,5,7 -> slots 0..3
    __syncthreads();
    if (!(wv & 1)) TILE_ADD(wv >> 1);           // waves 0,2,4,6 absorb partners
    __syncthreads();
    if (wv == 2 || wv == 6) TILE_STORE(wv >> 2);  // -> slots 0,1
    __syncthreads();
    if (wv == 0 || wv == 4) TILE_ADD(wv >> 2);
    __syncthreads();
    if (wv == 4) TILE_STORE(0);
    __syncthreads();
    if (wv == 0) {
        TILE_ADD(0);
#pragma unroll
        for (int tl = 0; tl < 2; ++tl)
#pragma unroll
            for (int et = 0; et < 4; ++et)
#pragma unroll
                for (int r = 0; r < 4; ++r) {
                    const int m = (kg << 2) + r;
                    red[(tl * 16 + m) * 68 + et * 16 + col16] = acc[tl][et][r];
                }
    }
    __syncthreads();

    // ---------------- epilogue: bias + stable top-2 + softmax (validated path) ----------------
    if (t < BM * 8) {
        const int row = t >> 3;   // 0..31
        const int g8  = t & 7;    // expert group of 8
        float l[8];
#pragma unroll
        for (int j = 0; j < 8; ++j)
            l[j] = red[row * 68 + g8 * 8 + j] + bias[g8 * 8 + j];

        float v0 = l[0];
        int   i0 = 8 * g8;
        float v1 = -INFINITY;
        int   i1 = -1;
#pragma unroll
        for (int j = 1; j < 8; ++j) {
            const float lv = l[j];
            const int   e  = 8 * g8 + j;
            if (lv > v0) { v1 = v0; i1 = i0; v0 = lv; i0 = e; }
            else if (lv > v1) { v1 = lv; i1 = e; }
        }
#pragma unroll
        for (int m2 = 1; m2 <= 4; m2 <<= 1) {
            const float ov0 = __shfl_xor(v0, m2);
            const int   oi0 = __shfl_xor(i0, m2);
            const float ov1 = __shfl_xor(v1, m2);
            const int   oi1 = __shfl_xor(i1, m2);
            if (gt_pair(ov0, oi0, v0, i0)) {
                if (gt_pair(v0, i0, ov1, oi1)) { v1 = v0; i1 = i0; }
                else                           { v1 = ov1; i1 = oi1; }
                v0 = ov0; i0 = oi0;
            } else if (gt_pair(ov0, oi0, v1, i1)) {
                v1 = ov0; i1 = oi0;
            }
        }
        float d = 0.f;
#pragma unroll
        for (int j = 0; j < 8; ++j) d += expf(l[j] - v0);
#pragma unroll
        for (int m2 = 1; m2 <= 4; m2 <<= 1) d += __shfl_xor(d, m2);

        if (g8 == 0) {
            const int R = r0 + row;
            out[2 * R]     = (float)i0;
            out[2 * R + 1] = (float)i1;
            out[2 * M + 2 * R]     = 1.f / d;
            out[2 * M + 2 * R + 1] = expf(v1 - v0) / d;
        }
    }
}

extern "C" void kernel_launch(void* const* d_in, const int* in_sizes, int n_in,
                              void* d_out, int out_size, void* d_ws, size_t ws_size,
                              hipStream_t stream) {
    const float* x  = (const float*)d_in[0];
    const float* W  = (const float*)d_in[1];
    const float* b  = (const float*)d_in[2];
    float* out = (float*)d_out;
    const int M = in_sizes[0] / DIMK;   // 16384 rows
    SwitchRouter_43078521979510_kernel<<<M / BM, 512, 0, stream>>>(x, W, b, out, M);
}

// Round 6
// 36.776 us; speedup vs baseline: 1.3321x; 1.2483x over previous
//
#include <hip/hip_runtime.h>
#include <math.h>

typedef _Float16 half8 __attribute__((ext_vector_type(8)));
typedef float f32x16 __attribute__((ext_vector_type(16)));

#define DIMK 2048
#define NEXP 64
#define BM 32                 // rows per block
#define NW 4                  // waves per block (k-split)
#define KPW (DIMK / NW)       // 512 k per wave
#define CHUNK 64              // k per staged chunk
#define NCHUNK (KPW / CHUNK)  // 8 chunks per wave
#define KSTEP 16              // k per 32x32x16 MFMA step
#define NKS (CHUNK / KSTEP)   // 4 ksteps per chunk
#define NU (NCHUNK * NKS)     // 32 ksteps total per wave

// ---------------- W pre-split kernel (R2-validated) ----------------
// ws layout (halfs): [kb8 = k/8][limb][e][k%8]  -> block of 512 halfs per (kb8,limb)
__global__ void SwitchRouter_wsplit(const float* __restrict__ W, _Float16* __restrict__ ws) {
    int t = blockIdx.x * 256 + threadIdx.x;
    if (t >= NEXP * DIMK) return;
    int e = t >> 11, k = t & (DIMK - 1);
    float w = W[e * DIMK + k];
    _Float16 h0 = (_Float16)w;
    _Float16 h1 = (_Float16)(w - (float)h0);
    int kb8 = k >> 3, kj = k & 7;
    ws[(((kb8 * 2 + 0) << 9) + (e << 3) + kj)] = h0;
    ws[(((kb8 * 2 + 1) << 9) + (e << 3) + kj)] = h1;
}

__device__ __forceinline__ bool gt_pair(float v, int i, float v2, int i2) {
    return (v > v2) || (v == v2 && i < i2);
}

__device__ __forceinline__ half8 ldw(const _Float16* wsp, int kglob0, int half_, int et, int limb, int row) {
    int kb8 = (kglob0 >> 3) + half_;
    return *(const half8*)(wsp + (((size_t)(kb8 * 2 + limb) << 9) + (((et << 5) + row) << 3)));
}

__global__ __launch_bounds__(256, 2)
void SwitchRouter_43078521979510_kernel(const float* __restrict__ x,
                                        const _Float16* __restrict__ wsp,
                                        const float* __restrict__ bias,
                                        float* __restrict__ out, int M)
{
    __shared__ float lds[16384];  // 64 KB: 4 waves x dbuf x (32 rows x 64 k fp32); reused for reduction

    const int t     = threadIdx.x;
    const int wv    = t >> 6;
    const int lane  = t & 63;
    const int row   = lane & 31;   // A row within tile / W expert within et-group
    const int half_ = lane >> 5;   // k sub-slice selector
    const int r0    = blockIdx.x * BM;
    const int kwb   = wv * KPW;

    float* atile = lds + wv * 4096;     // 2 bufs x 2048 floats
    const float* xg0 = x + (size_t)r0 * DIMK + kwb;

    // staging decomposition (R2-validated): instr j covers rows j*4+(lane>>4), granule lane&15 (XOR-swz)
#define STAGE(c)                                                                   \
    {                                                                              \
        float* dst = atile + ((c) & 1) * 2048;                                     \
        _Pragma("unroll") for (int j = 0; j < 8; ++j) {                            \
            const int rowj = j * 4 + (lane >> 4);                                  \
            const float* src = xg0 + (size_t)rowj * DIMK + (c) * CHUNK             \
                               + (((lane & 15) ^ (rowj & 15)) << 2);               \
            __builtin_amdgcn_global_load_lds(                                      \
                (const __attribute__((address_space(1))) void*)src,                \
                (__attribute__((address_space(3))) void*)(dst + j * 256),          \
                16, 0, 0);                                                         \
        }                                                                          \
    }

#define LOADW(u, slot)                                                             \
    {                                                                              \
        const int kg = kwb + (u) * KSTEP;                                          \
        wr[slot][0] = ldw(wsp, kg, half_, 0, 0, row);                              \
        wr[slot][1] = ldw(wsp, kg, half_, 0, 1, row);                              \
        wr[slot][2] = ldw(wsp, kg, half_, 1, 0, row);                              \
        wr[slot][3] = ldw(wsp, kg, half_, 1, 1, row);                              \
    }

    half8 wr[4][4];            // W ring: slot = u % 4 (= ks, static)
    f32x16 acc[2] = {};        // one accumulator per 32-expert tile

    // prologue program order fixes the vmcnt ledger: W(0),W(1),W(2) [12], A(0) [8], A(1) [8]
    LOADW(0, 0);
    LOADW(1, 1);
    LOADW(2, 2);
    STAGE(0);
    STAGE(1);

    for (int c = 0; c < NCHUNK; ++c) {
        // fence: require STAGE(c) landed. Steady-state leave-in-flight:
        // STAGE(c+1)[8] + W(next 3 ksteps)[12] (+W just-consumed[4] forced-retired) = 20.
        if (c == 0)              { asm volatile("s_waitcnt vmcnt(8)"  ::: "memory"); }
        else if (c == NCHUNK-1) { asm volatile("s_waitcnt vmcnt(0)"  ::: "memory"); }
        else                     { asm volatile("s_waitcnt vmcnt(20)" ::: "memory"); }

        const float* buf = atile + (c & 1) * 2048;

        // ---- hoisted A-fragment ds_reads for the whole chunk (XOR-swizzled granules) ----
        float4 fA[NKS], fB[NKS];
#pragma unroll
        for (int ks = 0; ks < NKS; ++ks) {
            const int g  = ks * 4 + half_ * 2;
            const int s0 = g ^ (row & 15);
            const int s1 = (g + 1) ^ (row & 15);
            fA[ks] = *(const float4*)&buf[row * 64 + s0 * 4];
            fB[ks] = *(const float4*)&buf[row * 64 + s1 * 4];
        }
        // buffer contents captured -> safe to restage this buffer
        asm volatile("s_waitcnt lgkmcnt(0)" ::: "memory");
        if (c + 2 < NCHUNK) STAGE(c + 2);

        // ---- 4 ksteps: W prefetch d=3 + limb conversion + 6 MFMAs ----
#pragma unroll
        for (int ks = 0; ks < NKS; ++ks) {
            const int u = c * NKS + ks;
            if (u + 3 < NU) LOADW(u + 3, (ks + 3) & 3);

            const float4 va = fA[ks], vb = fB[ks];
            const float f[8] = {va.x, va.y, va.z, va.w, vb.x, vb.y, vb.z, vb.w};
            half8 a0, a1;
#pragma unroll
            for (int j = 0; j < 8; ++j) {
                _Float16 h = (_Float16)f[j];
                a0[j] = h;
                a1[j] = (_Float16)(f[j] - (float)h);
            }

            const half8* w = wr[ks];   // slot = u % 4 = ks (static)
            acc[0] = __builtin_amdgcn_mfma_f32_32x32x16_f16(a0, w[0], acc[0], 0, 0, 0);
            acc[0] = __builtin_amdgcn_mfma_f32_32x32x16_f16(a1, w[0], acc[0], 0, 0, 0);
            acc[0] = __builtin_amdgcn_mfma_f32_32x32x16_f16(a0, w[1], acc[0], 0, 0, 0);
            acc[1] = __builtin_amdgcn_mfma_f32_32x32x16_f16(a0, w[2], acc[1], 0, 0, 0);
            acc[1] = __builtin_amdgcn_mfma_f32_32x32x16_f16(a1, w[2], acc[1], 0, 0, 0);
            acc[1] = __builtin_amdgcn_mfma_f32_32x32x16_f16(a0, w[3], acc[1], 0, 0, 0);
        }
    }

    // ---------------- cross-wave K reduction (R2-validated) ----------------
    __syncthreads();
    // reduce buffer: [wave][32 rows][68 pad] fp32 = 8704 floats (aliases atile space)
    float* red = lds;
    // D frag (32x32): col = lane&31, rowD = (s&3) + 8*(s>>2) + 4*half_
#pragma unroll
    for (int s = 0; s < 16; ++s) {
        const int rowD = (s & 3) + 8 * (s >> 2) + 4 * half_;
        red[wv * 2176 + rowD * 68 + 0 * 32 + row] = acc[0][s];
        red[wv * 2176 + rowD * 68 + 1 * 32 + row] = acc[1][s];
    }
    __syncthreads();

    // ---------------- epilogue: bias + stable top-2 + softmax (validated path) ----------------
    {
        const int rr = t >> 3;   // 0..31 row within block
        const int g8 = t & 7;    // expert-group 0..7
        float l[8];
#pragma unroll
        for (int j = 0; j < 8; ++j) {
            float s = 0.f;
#pragma unroll
            for (int w2 = 0; w2 < NW; ++w2) s += red[w2 * 2176 + rr * 68 + g8 * 8 + j];
            l[j] = s + bias[g8 * 8 + j];
        }

        float v0 = l[0];
        int   i0 = 8 * g8;
        float v1 = -INFINITY;
        int   i1 = -1;
#pragma unroll
        for (int j = 1; j < 8; ++j) {
            const float lv = l[j];
            const int   e  = 8 * g8 + j;
            if (lv > v0) { v1 = v0; i1 = i0; v0 = lv; i0 = e; }
            else if (lv > v1) { v1 = lv; i1 = e; }
        }
#pragma unroll
        for (int m2 = 1; m2 <= 4; m2 <<= 1) {
            const float ov0 = __shfl_xor(v0, m2);
            const int   oi0 = __shfl_xor(i0, m2);
            const float ov1 = __shfl_xor(v1, m2);
            const int   oi1 = __shfl_xor(i1, m2);
            if (gt_pair(ov0, oi0, v0, i0)) {
                if (gt_pair(v0, i0, ov1, oi1)) { v1 = v0; i1 = i0; }
                else                           { v1 = ov1; i1 = oi1; }
                v0 = ov0; i0 = oi0;
            } else if (gt_pair(ov0, oi0, v1, i1)) {
                v1 = ov0; i1 = oi0;
            }
        }
        float d = 0.f;
#pragma unroll
        for (int j = 0; j < 8; ++j) d += expf(l[j] - v0);
#pragma unroll
        for (int m2 = 1; m2 <= 4; m2 <<= 1) d += __shfl_xor(d, m2);

        if (g8 == 0) {
            const int R = r0 + rr;
            out[2 * R]     = (float)i0;
            out[2 * R + 1] = (float)i1;
            out[2 * M + 2 * R]     = 1.f / d;
            out[2 * M + 2 * R + 1] = expf(v1 - v0) / d;
        }
    }
}

extern "C" void kernel_launch(void* const* d_in, const int* in_sizes, int n_in,
                              void* d_out, int out_size, void* d_ws, size_t ws_size,
                              hipStream_t stream) {
    const float* x  = (const float*)d_in[0];
    const float* W  = (const float*)d_in[1];
    const float* b  = (const float*)d_in[2];
    float* out = (float*)d_out;
    _Float16* ws = (_Float16*)d_ws;
    const int M = in_sizes[0] / DIMK;   // 16384 rows

    SwitchRouter_wsplit<<<(NEXP * DIMK + 255) / 256, 256, 0, stream>>>(W, ws);
    SwitchRouter_43078521979510_kernel<<<M / BM, 256, 0, stream>>>(x, ws, b, out, M);
}

// Round 7
// 34.291 us; speedup vs baseline: 1.4287x; 1.0725x over previous
//
#include <hip/hip_runtime.h>
#include <math.h>

typedef _Float16 half8 __attribute__((ext_vector_type(8)));
typedef float f32x16 __attribute__((ext_vector_type(16)));

#define DIMK 2048
#define NEXP 64
#define BM 32                 // rows per block
#define NW 4                  // waves per block (k-split)
#define KPW (DIMK / NW)       // 512 k per wave
#define CHUNK 32              // k per staged chunk (halved vs R6 for occupancy)
#define NCHUNK (KPW / CHUNK)  // 16 chunks per wave
#define KSTEP 16              // k per 32x32x16 MFMA step
#define NKS (CHUNK / KSTEP)   // 2 ksteps per chunk
#define NU (KPW / KSTEP)      // 32 ksteps total per wave

// ---------------- W pre-split kernel (R2-validated) ----------------
// ws layout (halfs): [kb8 = k/8][limb][e][k%8]  -> block of 512 halfs per (kb8,limb)
__global__ void SwitchRouter_wsplit(const float* __restrict__ W, _Float16* __restrict__ ws) {
    int t = blockIdx.x * 256 + threadIdx.x;
    if (t >= NEXP * DIMK) return;
    int e = t >> 11, k = t & (DIMK - 1);
    float w = W[e * DIMK + k];
    _Float16 h0 = (_Float16)w;
    _Float16 h1 = (_Float16)(w - (float)h0);
    int kb8 = k >> 3, kj = k & 7;
    ws[(((kb8 * 2 + 0) << 9) + (e << 3) + kj)] = h0;
    ws[(((kb8 * 2 + 1) << 9) + (e << 3) + kj)] = h1;
}

__device__ __forceinline__ bool gt_pair(float v, int i, float v2, int i2) {
    return (v > v2) || (v == v2 && i < i2);
}

__device__ __forceinline__ half8 ldw(const _Float16* wsp, int kglob0, int half_, int et, int limb, int row) {
    int kb8 = (kglob0 >> 3) + half_;
    return *(const half8*)(wsp + (((size_t)(kb8 * 2 + limb) << 9) + (((et << 5) + row) << 3)));
}

__global__ __launch_bounds__(256, 3)
void SwitchRouter_43078521979510_kernel(const float* __restrict__ x,
                                        const _Float16* __restrict__ wsp,
                                        const float* __restrict__ bias,
                                        float* __restrict__ out, int M)
{
    __shared__ float lds[8704];   // 34.8 KB: 4 waves x dbuf x (32 rows x 32 k); aliased by reduction (4x2176)

    const int t     = threadIdx.x;
    const int wv    = t >> 6;
    const int lane  = t & 63;
    const int row   = lane & 31;   // A row within tile / W expert within et-group
    const int half_ = lane >> 5;   // k sub-slice selector
    const int r0    = blockIdx.x * BM;
    const int kwb   = wv * KPW;

    float* atile = lds + wv * 2048;     // 2 bufs x 1024 floats
    const float* xg0 = x + (size_t)r0 * DIMK + kwb;

    // staging: instr j covers rows j*8+(lane>>3), granule lane&7 (XOR-swizzled vs row&7)
#define STAGE(c)                                                                   \
    {                                                                              \
        float* dst = atile + ((c) & 1) * 1024;                                     \
        _Pragma("unroll") for (int j = 0; j < 4; ++j) {                            \
            const int rowj = j * 8 + (lane >> 3);                                  \
            const float* src = xg0 + (size_t)rowj * DIMK + (c) * CHUNK             \
                               + (((lane & 7) ^ (rowj & 7)) << 2);                 \
            __builtin_amdgcn_global_load_lds(                                      \
                (const __attribute__((address_space(1))) void*)src,                \
                (__attribute__((address_space(3))) void*)(dst + j * 256),          \
                16, 0, 0);                                                         \
        }                                                                          \
    }

#define LOADW(u, slot)                                                             \
    {                                                                              \
        const int kg = kwb + (u) * KSTEP;                                          \
        wr[slot][0] = ldw(wsp, kg, half_, 0, 0, row);                              \
        wr[slot][1] = ldw(wsp, kg, half_, 0, 1, row);                              \
        wr[slot][2] = ldw(wsp, kg, half_, 1, 0, row);                              \
        wr[slot][3] = ldw(wsp, kg, half_, 1, 1, row);                              \
    }

    half8 wr[4][4];            // W ring: slot = u % 4 (static under chunk-pair unroll)
    f32x16 acc[2] = {};        // one accumulator per 32-expert tile

    // prologue issue order fixes the vmcnt ledger: W(0),W(1),W(2) [12], A(0)[4], A(1)[4]
    LOADW(0, 0);
    LOADW(1, 1);
    LOADW(2, 2);
    STAGE(0);
    STAGE(1);

    // chunk-pair loop keeps ring slot (u&3) and dbuf index compile-time static
    for (int cb = 0; cb < NCHUNK / 2; ++cb) {
#pragma unroll
        for (int pc = 0; pc < 2; ++pc) {
            const int c = 2 * cb + pc;              // c & 1 == pc (static)
            // fence: W(2c),W(2c+1) + STAGE(c) retired. Younger-than-W(2c+1) in the
            // in-order queue = the single next LOADW (4). Last chunk: drain all.
            if (cb == NCHUNK / 2 - 1 && pc == 1) {
                asm volatile("s_waitcnt vmcnt(0)" ::: "memory");
            } else {
                asm volatile("s_waitcnt vmcnt(4)" ::: "memory");
            }

            const float* buf = atile + pc * 1024;

            // ---- hoisted A-fragment ds_reads for both ksteps (XOR-swizzled granules) ----
            float4 fA[NKS], fB[NKS];
#pragma unroll
            for (int ks = 0; ks < NKS; ++ks) {
                const int g  = ks * 4 + half_ * 2;
                const int s0 = g ^ (row & 7);
                const int s1 = (g + 1) ^ (row & 7);
                fA[ks] = *(const float4*)&buf[row * 32 + s0 * 4];
                fB[ks] = *(const float4*)&buf[row * 32 + s1 * 4];
            }
            // buffer captured -> safe to restage this buffer
            asm volatile("s_waitcnt lgkmcnt(0)" ::: "memory");
            if (c + 2 < NCHUNK) STAGE(c + 2);

            // ---- 2 ksteps: W prefetch d=3 + limb conversion + 6 MFMAs ----
#pragma unroll
            for (int ks = 0; ks < NKS; ++ks) {
                const int u = c * NKS + ks;                  // = 4*cb + 2*pc + ks
                const int slot = (2 * pc + ks) & 3;          // u & 3 (static)
                if (u + 3 < NU) LOADW(u + 3, (slot + 3) & 3);

                const float4 va = fA[ks], vb = fB[ks];
                const float f[8] = {va.x, va.y, va.z, va.w, vb.x, vb.y, vb.z, vb.w};
                half8 a0, a1;
#pragma unroll
                for (int j = 0; j < 8; ++j) {
                    _Float16 h = (_Float16)f[j];
                    a0[j] = h;
                    a1[j] = (_Float16)(f[j] - (float)h);
                }

                const half8* w = wr[slot];
                acc[0] = __builtin_amdgcn_mfma_f32_32x32x16_f16(a0, w[0], acc[0], 0, 0, 0);
                acc[0] = __builtin_amdgcn_mfma_f32_32x32x16_f16(a1, w[0], acc[0], 0, 0, 0);
                acc[0] = __builtin_amdgcn_mfma_f32_32x32x16_f16(a0, w[1], acc[0], 0, 0, 0);
                acc[1] = __builtin_amdgcn_mfma_f32_32x32x16_f16(a0, w[2], acc[1], 0, 0, 0);
                acc[1] = __builtin_amdgcn_mfma_f32_32x32x16_f16(a1, w[2], acc[1], 0, 0, 0);
                acc[1] = __builtin_amdgcn_mfma_f32_32x32x16_f16(a0, w[3], acc[1], 0, 0, 0);
            }
        }
    }

    // ---------------- cross-wave K reduction (R2-validated) ----------------
    __syncthreads();
    float* red = lds;   // [wave][32 rows][68 pad] = 4 x 2176 floats
    // D frag (32x32): col = lane&31, rowD = (s&3) + 8*(s>>2) + 4*half_
#pragma unroll
    for (int s = 0; s < 16; ++s) {
        const int rowD = (s & 3) + 8 * (s >> 2) + 4 * half_;
        red[wv * 2176 + rowD * 68 + 0 * 32 + row] = acc[0][s];
        red[wv * 2176 + rowD * 68 + 1 * 32 + row] = acc[1][s];
    }
    __syncthreads();

    // ---------------- epilogue: bias + stable top-2 + softmax (validated path) ----------------
    {
        const int rr = t >> 3;   // 0..31 row within block
        const int g8 = t & 7;    // expert-group 0..7
        float l[8];
#pragma unroll
        for (int j = 0; j < 8; ++j) {
            float s = 0.f;
#pragma unroll
            for (int w2 = 0; w2 < NW; ++w2) s += red[w2 * 2176 + rr * 68 + g8 * 8 + j];
            l[j] = s + bias[g8 * 8 + j];
        }

        float v0 = l[0];
        int   i0 = 8 * g8;
        float v1 = -INFINITY;
        int   i1 = -1;
#pragma unroll
        for (int j = 1; j < 8; ++j) {
            const float lv = l[j];
            const int   e  = 8 * g8 + j;
            if (lv > v0) { v1 = v0; i1 = i0; v0 = lv; i0 = e; }
            else if (lv > v1) { v1 = lv; i1 = e; }
        }
#pragma unroll
        for (int m2 = 1; m2 <= 4; m2 <<= 1) {
            const float ov0 = __shfl_xor(v0, m2);
            const int   oi0 = __shfl_xor(i0, m2);
            const float ov1 = __shfl_xor(v1, m2);
            const int   oi1 = __shfl_xor(i1, m2);
            if (gt_pair(ov0, oi0, v0, i0)) {
                if (gt_pair(v0, i0, ov1, oi1)) { v1 = v0; i1 = i0; }
                else                           { v1 = ov1; i1 = oi1; }
                v0 = ov0; i0 = oi0;
            } else if (gt_pair(ov0, oi0, v1, i1)) {
                v1 = ov0; i1 = oi0;
            }
        }
        float d = 0.f;
#pragma unroll
        for (int j = 0; j < 8; ++j) d += expf(l[j] - v0);
#pragma unroll
        for (int m2 = 1; m2 <= 4; m2 <<= 1) d += __shfl_xor(d, m2);

        if (g8 == 0) {
            const int R = r0 + rr;
            out[2 * R]     = (float)i0;
            out[2 * R + 1] = (float)i1;
            out[2 * M + 2 * R]     = 1.f / d;
            out[2 * M + 2 * R + 1] = expf(v1 - v0) / d;
        }
    }
}

extern "C" void kernel_launch(void* const* d_in, const int* in_sizes, int n_in,
                              void* d_out, int out_size, void* d_ws, size_t ws_size,
                              hipStream_t stream) {
    const float* x  = (const float*)d_in[0];
    const float* W  = (const float*)d_in[1];
    const float* b  = (const float*)d_in[2];
    float* out = (float*)d_out;
    _Float16* ws = (_Float16*)d_ws;
    const int M = in_sizes[0] / DIMK;   // 16384 rows

    SwitchRouter_wsplit<<<(NEXP * DIMK + 255) / 256, 256, 0, stream>>>(W, ws);
    SwitchRouter_43078521979510_kernel<<<M / BM, 256, 0, stream>>>(x, ws, b, out, M);
}